// Round 10
// baseline (1762.468 us; speedup 1.0000x reference)
//
#include <hip/hip_runtime.h>
#include <cstdint>
#include <cstddef>

// BooleanReservoir — persistent kernel, v13: strict per-step rendezvous (PACE=1,
// the R5-R8 lesson) but with the three serial chain links overlapped:
//   (1) NO vmcnt drain before arrival: per-step tag-pair buffers st[0..128]
//       ((D, G=D^KTAG), proven R5-R8) carry visibility; arrival RMW fires while
//       result stores are still in flight. No __syncthreads in the step loop —
//       block coordination via LDS (warr[4] arrival ring + go_lds broadcast,
//       v11-proven machinery).
//   (2) SPECULATIVE gather: the step-t+1 pair-gather is issued right after
//       arrival, flying during the 2-3 RTT go-wait; after the gate a masked
//       validation loop fixes rare stale lanes (stores had >=2 RTT to land).
//   (3) dynamic per-step block master (8th LDS-arriver) does the single global
//       arrival RMW (512/step = 8/counter, v4-proven load) and the go poll
//       (64 wave-pollers/line, v4-proven), then LDS-broadcasts.
// Step chain: arrive(0.7us) + leader observe(<=1) + go(0.7) + spin(0.5) +
// validate(~0) + compute(0.2) ~= 3us vs v4's 4.15 (drain + post-barrier gather
// were serial there).
// Deadlock-free: st[0] prefilled valid; gate for step t+1 = go>=t+1, published
// after all 512 per-block arrivals for step t; every wave arrives before
// spinning; validation terminates (producer stores are in flight, land in
// finite time). warr slot reuse is 4 steps (>=3 full gated steps) after reset.

#define N_NODES   20000
#define N_INPUT   64
#define K_MAX     12
#define T_STEPS   128
#define N_BATCH   64
#define N_OUT     10
#define N_FEAT    (N_NODES - N_INPUT)   // 19936
#define DUMMY_NODE 20000                // always-zero, always-valid entry
#define ST_WORDS  20004
#define T_BUF     (T_STEPS + 1)         // st[0..128]

#define NBLK 512
#define NTHR 512                        // 8 waves/block, 2 blocks/CU
#define NPB  39                         // 512*39 = 19968 >= 19936
#define NPB_PAD 40                      // 8 waves * 5 nodes
#define BAR_CNT 64                      // arrival counters: 8 blocks/counter
#define GO_CNT  8                       // go lines: 64 wave-pollers/line
#define BAR_STRIDE 32                   // u32 units -> 128 B apart

#define KTAG 0x9E3779B97F4A7C15ull

#define RO_CHUNK 32                     // 19936 = 32 * 623
#define RO_NPC   623

typedef unsigned long long u64;

#define ALOAD(p)    __hip_atomic_load((p),  __ATOMIC_RELAXED, __HIP_MEMORY_SCOPE_AGENT)
#define ASTORE(p,v) __hip_atomic_store((p), (v), __ATOMIC_RELAXED, __HIP_MEMORY_SCOPE_AGENT)

// ---- fused prep: blocks 0..127 -> u(t) pairs into st[t][0..63]; block 128 -> bar ----
__global__ __launch_bounds__(256) void prep_kernel(const int* __restrict__ x,
                                                   const int* __restrict__ w_in,
                                                   u64* __restrict__ st,
                                                   unsigned* __restrict__ bar) {
  const int wave = threadIdx.x >> 6, lane = threadIdx.x & 63;
  if (blockIdx.x < T_STEPS) {
    const int t = blockIdx.x;
    __shared__ u64 xp_lds[N_BATCH];          // xp[t][b]
    __shared__ u64 wcol_lds[64];             // input weight columns
    for (int b = wave; b < N_BATCH; b += 4) {
      int v = x[((size_t)b * T_STEPS + t) * 64 + lane];   // lane = bit j
      u64 bal = __ballot(v != 0);
      if (lane == 0) xp_lds[b] = bal;
    }
    for (int i = wave; i < 64; i += 4) {
      int wv = w_in[(size_t)lane * 64 + i];  // lane = j
      u64 wc = __ballot(wv != 0);
      if (lane == 0) wcol_lds[i] = wc;
    }
    __syncthreads();
    u64 xw = xp_lds[lane];                   // lane = batch b
    for (int i = wave; i < 64; i += 4) {
      u64 ub = __ballot((xw & wcol_lds[i]) != 0);   // u(t)[b][i]
      if (lane == 0) {
        u64* p = st + ((size_t)t * ST_WORDS + i) * 2;
        p[0] = ub;
        p[1] = ub ^ KTAG;                    // valid pair
      }
    }
  } else {
    if (threadIdx.x < BAR_CNT + GO_CNT)      // ws re-poisoned each call
      bar[threadIdx.x * BAR_STRIDE] = 0u;
  }
}

// -------- prefill all 129 step buffers for n>=64 (pairs), re-run every call --------
// t=0: valid init pairs. t>=1: has-neigh -> INVALID (0, ~KTAG);
// no-neigh -> valid init pair (kept forever); dummy/pad -> valid (0, KTAG).
__global__ __launch_bounds__(512) void fill_kernel(const int* __restrict__ mask,
                                                   const int* __restrict__ inis,
                                                   u64* __restrict__ st) {
  int n = N_INPUT + blockIdx.x * 512 + threadIdx.x;   // [64, 20032)
  if (n >= ST_WORDS) return;
  bool hn = false; u64 iw = 0;
  if (n < N_NODES) {
    int h = 0;
    for (int j = 0; j < K_MAX; j++) h |= mask[(size_t)n * K_MAX + j];
    hn = (h != 0);
    iw = inis[n] ? ~0ull : 0ull;
  }
  const u64 dt0 = iw,             gt0 = iw ^ KTAG;
  const u64 dtr = hn ? 0ull : iw, gtr = hn ? ~KTAG : (iw ^ KTAG);
  const int t0 = blockIdx.y * 4, t1 = min(t0 + 4, T_BUF);
  for (int t = t0; t < t1; t++) {
    u64 d = (t == 0) ? dt0 : dtr, g = (t == 0) ? gt0 : gtr;
    st[((size_t)t * ST_WORDS + n) * 2]     = d;    // coalesced 16B/thread
    st[((size_t)t * ST_WORDS + n) * 2 + 1] = g;
  }
}

// ---- 64x64 bit transpose: lane l holds row l; returns lane b holding column b ----
__device__ __forceinline__ u64 bit_transpose64(u64 w, int lane) {
  const u64 LO0 = 0x00000000FFFFFFFFull, LO1 = 0x0000FFFF0000FFFFull,
            LO2 = 0x00FF00FF00FF00FFull, LO3 = 0x0F0F0F0F0F0F0F0Full,
            LO4 = 0x3333333333333333ull, LO5 = 0x5555555555555555ull;
#define XP_STAGE(d, LO)                                                  \
  {                                                                      \
    u64 p = (u64)__shfl_xor((long long)w, (d), 64);                      \
    if (lane & (d)) w = ((p >> (d)) & (LO)) | (w & ~(LO));               \
    else            w = (w & (LO)) | ((p << (d)) & ~(LO));               \
  }
  XP_STAGE(32, LO0) XP_STAGE(16, LO1) XP_STAGE(8, LO2)
  XP_STAGE(4,  LO3) XP_STAGE(2,  LO4) XP_STAGE(1, LO5)
#undef XP_STAGE
  return w;
}

// ---------------- persistent reservoir: 128 strict-gated steps ----------------
__global__ __launch_bounds__(NTHR, 4) void reservoir_kernel(
    const int* __restrict__ lut, const int* __restrict__ adj,
    const int* __restrict__ mask, u64* __restrict__ st,
    unsigned* __restrict__ bar) {
  __shared__ u64 lut_lds[NPB_PAD * 64];        // 20480 B
  __shared__ int adj_lds[NPB_PAD * K_MAX];     //  1920 B
  __shared__ unsigned char hn_lds[NPB_PAD];
  __shared__ unsigned warr[4];                 // arrival ring (slot = t & 3)
  __shared__ unsigned go_lds;                  // block-local go broadcast

  const int bi = blockIdx.x;
  const int tid = threadIdx.x;
  const int wave = tid >> 6, lane = tid & 63;
  const int base = N_INPUT + bi * NPB;
  const int nloc = min(NPB, N_NODES - base);   // last block: 7

  if (tid < 4) warr[tid] = 0u;
  if (tid == 0) go_lds = 0u;

  // ---- prologue: adjacency (slot-REVERSED: slot j at offset 11-j) + hn ----
  if (tid < NPB_PAD) {
    int i = tid, h = 0;
    if (i < nloc) {
      for (int j = 0; j < K_MAX; j++) {
        int m = mask[(size_t)(base + i) * K_MAX + j];
        int a = adj[(size_t)(base + i) * K_MAX + j];
        adj_lds[i * K_MAX + (K_MAX - 1 - j)] = m ? a : DUMMY_NODE;
        h |= m;
      }
    } else {
      for (int j = 0; j < K_MAX; j++) adj_lds[i * K_MAX + j] = DUMMY_NODE;
    }
    hn_lds[i] = (unsigned char)(h ? 1 : 0);
  }

  // ---- prologue: pack this block's LUT slice into LDS (proven v4 path) ----
  const int nwords = nloc * 64;
  const int* lp = lut + (size_t)base * 4096;
  for (int w0 = wave * 8; w0 < nwords; w0 += 64) {
    int v[8];
#pragma unroll
    for (int q = 0; q < 8; q++) {
      int widx = w0 + q;
      v[q] = (widx < nwords) ? lp[(size_t)widx * 64 + lane] : 0;   // coalesced 256B
    }
#pragma unroll
    for (int q = 0; q < 8; q++) {
      int widx = w0 + q;
      u64 bal = __ballot(v[q] != 0);
      if (lane == 0 && widx < nwords) lut_lds[widx] = bal;
    }
  }
  __syncthreads();   // block-local, prologue only; step loop has NO syncthreads

  const int l0 = wave * 5;                     // this wave's first local node
  const int cnt = min(5, nloc - l0);           // may be <= 0

  int a0 = DUMMY_NODE;                         // lanes 60-63: constant-valid pair
  if (lane < 60) a0 = adj_lds[l0 * K_MAX + lane];
  unsigned hmask = 0;
#pragma unroll
  for (int i = 0; i < 5; i++) hmask |= (unsigned)hn_lds[l0 + i] << i;

  unsigned* cntp = &bar[(bi & (BAR_CNT - 1)) * BAR_STRIDE];
  unsigned* gop  = &bar[(BAR_CNT + (bi & (GO_CNT - 1))) * BAR_STRIDE];

  // initial gather: st[0] is prefilled valid (prep/fill are launch-ordered)
  u64 d = 0, g = KTAG;
  if (lane < 60) {
    d = ALOAD(&st[2 * a0]);
    g = ALOAD(&st[2 * a0 + 1]);
  }

  // ---- 128 steps ----
  for (int t = 0; t < T_STEPS; t++) {
    const u64* stc = st + (size_t)t * ST_WORDS * 2;
    u64* stn = st + (size_t)(t + 1) * ST_WORDS * 2;

    // finalize gather: masked validation (spec data usually valid already)
    int rounds = 0;
    while (!__all((d ^ g) == KTAG)) {
      if (++rounds > 2) __builtin_amdgcn_s_sleep(1);
      if ((d ^ g) != KTAG) {                   // exec-masked reload
        d = ALOAD(&stc[2 * a0]);
        g = ALOAD(&stc[2 * a0 + 1]);
      }
    }
    u64 w = bit_transpose64(d, lane);          // lane b: 60 index bits for batch b

#pragma unroll
    for (int i = 0; i < 5; i++) {
      if (i < cnt) {                           // wave-uniform
        unsigned idx = (unsigned)(w >> (12 * i)) & 0xFFFu;   // MSB-first index
        u64 gl = lut_lds[(l0 + i) * 64 + (idx >> 6)];
        u64 res = __ballot((gl >> (idx & 63)) & 1ull);
        if (((hmask >> i) & 1u) && lane < 2) { // lane0: D, lane1: G (parallel)
          u64 val = lane ? (res ^ KTAG) : res;
          ASTORE(&stn[2 * (base + l0 + i) + lane], val);
        }
      }
    }

    // ---- per-step strict gate: arrive (no drain) -> spec gather -> go ----
    if (t != T_STEPS - 1) {
      const unsigned nt = (unsigned)(t + 1);
      unsigned old = 0;
      if (lane == 0) old = atomicAdd(&warr[t & 3], 1u);     // LDS arrival
      old = (unsigned)__shfl((int)old, 0);
      const bool master = (old == 7u);
      if (master && lane == 0)                 // one global RMW per block/step
        __hip_atomic_fetch_add(cntp, 1u, __ATOMIC_RELAXED, __HIP_MEMORY_SCOPE_AGENT);

      // speculative gather for step t+1 — flies during the go-wait
      d = 0; g = KTAG;
      if (lane < 60) {
        d = ALOAD(&stn[2 * a0]);
        g = ALOAD(&stn[2 * a0 + 1]);
      }

      if (bi == 0 && wave == 0) {
        // leader: poll 64 counters (one 64-lane load/round), publish go lines
        const unsigned tgt = nt * (NBLK / BAR_CNT);
        for (;;) {
          unsigned c = ALOAD(&bar[lane * BAR_STRIDE]);
          if (__all(c >= tgt)) break;
        }
        if (lane < GO_CNT)
          ASTORE(&bar[(BAR_CNT + lane) * BAR_STRIDE], nt);
        if (lane == 0) {
          warr[t & 3] = 0u;                    // slot reused at t+4 (safe gap)
          __threadfence_block();
          __hip_atomic_store(&go_lds, nt, __ATOMIC_RELAXED, __HIP_MEMORY_SCOPE_WORKGROUP);
        }
      } else if (master) {
        // master wave: uniform-address go poll (one L3 request/round)
        while (ALOAD(gop) < nt) { /* spin */ }
        if (lane == 0) {
          warr[t & 3] = 0u;
          __threadfence_block();
          __hip_atomic_store(&go_lds, nt, __ATOMIC_RELAXED, __HIP_MEMORY_SCOPE_WORKGROUP);
        }
      } else {
        // other waves: LDS spin (no fabric traffic)
        while (__hip_atomic_load(&go_lds, __ATOMIC_RELAXED,
                                 __HIP_MEMORY_SCOPE_WORKGROUP) < nt) { /* spin */ }
      }
    }
  }
}

// ---- readout part: partial[c][o][b] = sum over chunk c of W[o][n]*bit(n,b) ----
__global__ __launch_bounds__(256) void readout_part(const u64* __restrict__ st128,
                                                    const float* __restrict__ Wout,
                                                    float* __restrict__ partial) {
  const int c = blockIdx.x / N_OUT;            // 0..31
  const int o = blockIdx.x % N_OUT;
  const int b = threadIdx.x & 63, k = threadIdx.x >> 6;   // lane = batch
  const int n0 = c * RO_NPC, n1 = n0 + RO_NPC;
  float acc = 0.f;
  for (int n = n0 + k; n < n1; n += 4) {
    u64 s = st128[2 * (N_INPUT + n)];          // D half; wave-uniform broadcast
    float w = Wout[(size_t)o * N_FEAT + n];
    acc += ((s >> b) & 1ull) ? w : 0.f;
  }
  __shared__ float red[4][64];
  red[k][b] = acc;
  __syncthreads();
  if (threadIdx.x < 64) {
    float tot = red[0][b] + red[1][b] + red[2][b] + red[3][b];
    partial[((size_t)c * N_OUT + o) * 64 + b] = tot;
  }
}

// ---- readout final: out[b][o] = sigmoid(sum_c partial + bias) ----
__global__ __launch_bounds__(640) void readout_final(const float* __restrict__ partial,
                                                     const float* __restrict__ bout,
                                                     float* __restrict__ out) {
  const int b = threadIdx.x & 63, o = threadIdx.x >> 6;   // 640 threads
  float tot = bout[o];
  for (int c = 0; c < RO_CHUNK; c++)
    tot += partial[((size_t)c * N_OUT + o) * 64 + b];
  out[(size_t)b * N_OUT + o] = 1.f / (1.f + __expf(-tot));
}

extern "C" void kernel_launch(void* const* d_in, const int* in_sizes, int n_in,
                              void* d_out, int out_size, void* d_ws, size_t ws_size,
                              hipStream_t stream) {
  const int* x    = (const int*)d_in[0];
  const int* w_in = (const int*)d_in[1];
  const int* adj  = (const int*)d_in[2];
  const int* mask = (const int*)d_in[3];
  const int* lut  = (const int*)d_in[4];
  const int* inis = (const int*)d_in[5];
  const float* Wout = (const float*)d_in[6];
  const float* bout = (const float*)d_in[7];
  float* out = (float*)d_out;

  char* ws = (char*)d_ws;
  size_t off = 0;
  auto alloc = [&](size_t bytes) -> void* {
    void* p = ws + off;
    off += (bytes + 255) & ~(size_t)255;
    return p;
  };
  u64* st_all = (u64*)alloc((size_t)T_BUF * ST_WORDS * 16);   // 41.3 MB (pairs)
  unsigned* bar = (unsigned*)alloc((size_t)(BAR_CNT + GO_CNT) * BAR_STRIDE * 4);
  float* partial = (float*)alloc((size_t)RO_CHUNK * N_OUT * 64 * 4);  // 80 KB
  (void)ws_size; (void)in_sizes; (void)n_in; (void)out_size;

  hipLaunchKernelGGL(prep_kernel, dim3(T_STEPS + 1), dim3(256), 0, stream,
                     x, w_in, st_all, bar);
  hipLaunchKernelGGL(fill_kernel, dim3(39, 33), dim3(512), 0, stream,
                     mask, inis, st_all);

  hipLaunchKernelGGL(reservoir_kernel, dim3(NBLK), dim3(NTHR), 0, stream,
                     lut, adj, mask, st_all, bar);

  // final states live in st[128] (D halves)
  hipLaunchKernelGGL(readout_part, dim3(RO_CHUNK * N_OUT), dim3(256), 0, stream,
                     st_all + (size_t)T_STEPS * ST_WORDS * 2, Wout, partial);
  hipLaunchKernelGGL(readout_final, dim3(1), dim3(640), 0, stream,
                     partial, bout, out);
}